// Round 6
// baseline (143.013 us; speedup 1.0000x reference)
//
#include <hip/hip_runtime.h>

// Problem constants (from reference setup_inputs) — all tensors are fp32.
#define BATCH 16
#define NVEC 1024
#define NDIM 64
#define NHID 32
#define NW   10
#define NCLS 10
#define NOFF 11      // diag + 10 power-of-2 offsets (chord mask: 11 nnz/row)
#define WPAD 12      // padded weights-per-row so k_chain reads 3x float4

// ---------------------------------------------------------------------------
// Kernel 0: transpose fW2 [i][j][m] -> W2T [i][m][j] so the k_weights gather
// reads a row of 32 consecutive j's as 8 float4. LDS-tiled, 1.3 MB total.
// ---------------------------------------------------------------------------
__global__ __launch_bounds__(256) void k_transpose(
    const float* __restrict__ fW2, float* __restrict__ W2T)
{
    __shared__ float tile[NHID][65];   // +1 pad: conflict-free transposed reads
    const int i = blockIdx.y;
    const int m0 = blockIdx.x * 64;
    const int t = threadIdx.x;
    const int tL = t & 63, wv = t >> 6;

    const float* src = fW2 + (size_t)i * NHID * NVEC;
    #pragma unroll
    for (int jj = 0; jj < 8; ++jj) {
        int j = wv * 8 + jj;
        tile[j][tL] = src[(size_t)j * NVEC + m0 + tL];   // 256B coalesced
    }
    __syncthreads();

    float* dst = W2T + (size_t)i * NVEC * NHID;
    const int j = t & 31, mrow = t >> 5;
    #pragma unroll
    for (int g = 0; g < 8; ++g) {
        int m = g * 8 + mrow;
        dst[(size_t)(m0 + m) * NHID + j] = tile[j][m];   // coalesced
    }
}

// ---------------------------------------------------------------------------
// Kernel 1: all sparse chord weights, all 10 layers (h depends only on data).
// Thread = one (b, n) row with a FULL h[32] accumulator. W1/b1 addresses are
// wave-uniform (layer = blockIdx.y only) -> compiler emits s_load + FMAs with
// SGPR operands: NO LDS, no shfl (rounds 3-5 paid a ~13us device-wide LDS
// issue floor for W1 broadcasts). launch_bounds(256,1) lifts the VGPR cap to
// 512 so the ~70-reg live set cannot spill (rounds 2/4 died to scratch).
// Wave layout n = t&15: the W2T gather reads 16 consecutive 128B rows ->
// contiguous 2KB per instruction, 4x b-duplicated (L1/L2 broadcast).
// Gather loop is unroll-1 with direct scalar stores: no indexed local array.
// grid (NVEC/16, NW), block 256.
// ---------------------------------------------------------------------------
__global__ __launch_bounds__(256, 1) void k_weights(
    const float* __restrict__ data,   // [B][NVEC][NDIM]
    const float* __restrict__ fW1,    // [NW][NDIM][NHID]
    const float* __restrict__ fb1,    // [NW][NHID]
    const float* __restrict__ W2T,    // [NW][NVEC][NHID]  (transposed fW2)
    const float* __restrict__ fb2,    // [NW][NVEC]
    float* __restrict__ Wsp)          // [NW][B][NVEC][WPAD]
{
    const int i  = blockIdx.y;
    const int t  = threadIdx.x;
    const int nl = t & 15;
    const int b  = t >> 4;
    const int n  = blockIdx.x * 16 + nl;

    // h = b1 (wave-uniform scalar loads)
    const float* w1 = fW1 + (size_t)i * NDIM * NHID;
    const float* b1 = fb1 + (size_t)i * NHID;
    float h[NHID];
    #pragma unroll
    for (int j = 0; j < NHID; ++j) h[j] = b1[j];

    // h += data[b,n,:] @ W1[i]  (A row streamed as float4; W1 via SGPR)
    const float4* arow = (const float4*)(data + ((size_t)(b * NVEC) + n) * NDIM);
    #pragma unroll 2
    for (int g = 0; g < 16; ++g) {
        float4 a = arow[g];
        float xs[4] = {a.x, a.y, a.z, a.w};
        #pragma unroll
        for (int dk = 0; dk < 4; ++dk) {
            float x = xs[dk];
            const float* wr = w1 + (g * 4 + dk) * NHID;   // wave-uniform
            #pragma unroll
            for (int j = 0; j < NHID; ++j) h[j] += x * wr[j];
        }
    }

    // exact gelu
    #pragma unroll
    for (int j = 0; j < NHID; ++j) {
        float x = h[j];
        h[j] = 0.5f * x * (1.0f + erff(x * 0.70710678118654752f));
    }

    // 11 sparse columns: w[o] = h . W2T[m_o] + fb2[m_o], m_o = (n+off)%1024
    const float* w2t = W2T + (size_t)i * NVEC * NHID;
    const float* b2  = fb2 + (size_t)i * NVEC;
    float* wout = Wsp + ((size_t)(i * BATCH + b) * NVEC + n) * WPAD;
    #pragma unroll 1
    for (int o = 0; o < NOFF; ++o) {
        int off = (o == 0) ? 0 : (1 << (o - 1));
        int m = (n + off) & (NVEC - 1);
        const float4* gp = (const float4*)(w2t + (size_t)m * NHID);
        float acc = b2[m];
        #pragma unroll
        for (int k = 0; k < 8; ++k) {
            float4 gv = gp[k];
            acc += h[k * 4 + 0] * gv.x + h[k * 4 + 1] * gv.y
                 + h[k * 4 + 2] * gv.z + h[k * 4 + 3] * gv.w;
        }
        wout[o] = acc;   // 16 n-lanes at 48B stride: compact scatter
    }
}

// ---------------------------------------------------------------------------
// Kernel 2: FUSED 10-layer chain + final-projection partials.
// Block = (b, 4-dim chunk): V[1024][4] slice closed under the chord gather,
// kept in LDS float4 (all gathers aligned ds_read_b128). 1024 threads =
// 16 waves. Next layer's 11 weights (3 float4, row-padded) prefetched into
// registers so the loads are in flight across the barrier. 1 barrier/layer.
// grid (16 chunks, BATCH), block 1024.
// ---------------------------------------------------------------------------
__global__ __launch_bounds__(1024) void k_chain(
    const float* __restrict__ data,   // [B][NVEC][NDIM]
    const float* __restrict__ Wsp,    // [NW][B][NVEC][WPAD]
    const float* __restrict__ Wf,     // [NVEC*NDIM][NCLS]
    float* __restrict__ part)         // [B][16][NCLS]
{
    const int chunk = blockIdx.x;
    const int b     = blockIdx.y;
    const int d0    = chunk * 4;
    const int n     = threadIdx.x;

    __shared__ float4 bufA[NVEC];
    __shared__ float4 bufB[NVEC];

    bufA[n] = *(const float4*)(data + ((size_t)(b * NVEC) + n) * NDIM + d0);

    // prefetch layer NW-1 weights
    const float4* wp = (const float4*)(Wsp + ((size_t)((NW - 1) * BATCH + b) * NVEC + n) * WPAD);
    float4 wa = wp[0], wb4 = wp[1], wc = wp[2];
    __syncthreads();

    float4* cur = bufA;
    float4* nxt = bufB;

    for (int l = 0; l < NW; ++l) {
        float4 na, nb, nc;
        if (l < NW - 1) {   // prefetch next layer (in flight across barrier)
            const float4* wpn = (const float4*)(
                Wsp + ((size_t)((NW - 2 - l) * BATCH + b) * NVEC + n) * WPAD);
            na = wpn[0]; nb = wpn[1]; nc = wpn[2];
        }
        const float wgt[12] = {wa.x, wa.y, wa.z, wa.w,
                               wb4.x, wb4.y, wb4.z, wb4.w,
                               wc.x, wc.y, wc.z, wc.w};
        float4 v0 = cur[n];
        float4 acc;
        acc.x = v0.x + wgt[0] * v0.x;
        acc.y = v0.y + wgt[0] * v0.y;
        acc.z = v0.z + wgt[0] * v0.z;
        acc.w = v0.w + wgt[0] * v0.w;
        #pragma unroll
        for (int o = 1; o < NOFF; ++o) {
            int off = 1 << (o - 1);
            float4 vv = cur[(n + off) & (NVEC - 1)];
            acc.x += wgt[o] * vv.x; acc.y += wgt[o] * vv.y;
            acc.z += wgt[o] * vv.z; acc.w += wgt[o] * vv.w;
        }
        nxt[n] = acc;
        __syncthreads();
        float4* tmp = cur; cur = nxt; nxt = tmp;
        if (l < NW - 1) { wa = na; wb4 = nb; wc = nc; }
    }

    // fused final projection partial over this (b, d-chunk)
    float p[NCLS];
    #pragma unroll
    for (int c = 0; c < NCLS; ++c) p[c] = 0.0f;
    {
        float4 vv = cur[n];
        float vs[4] = {vv.x, vv.y, vv.z, vv.w};
        const float4* wfv = (const float4*)(Wf + ((size_t)(n * NDIM + d0)) * NCLS);
        float wf[40];
        #pragma unroll
        for (int k = 0; k < 10; ++k) {
            float4 u = wfv[k];
            wf[k * 4 + 0] = u.x; wf[k * 4 + 1] = u.y;
            wf[k * 4 + 2] = u.z; wf[k * 4 + 3] = u.w;
        }
        #pragma unroll
        for (int d = 0; d < 4; ++d)
            #pragma unroll
            for (int cls = 0; cls < NCLS; ++cls)
                p[cls] += vs[d] * wf[d * NCLS + cls];
    }

    // reduce 1024 threads -> 10 values: wave shfl then cross-wave via LDS
    const int lane = n & 63, wv = n >> 6;   // 16 waves
    float* sred = (float*)nxt;              // dead buffer
    #pragma unroll
    for (int cls = 0; cls < NCLS; ++cls) {
        float v = p[cls];
        #pragma unroll
        for (int s = 32; s > 0; s >>= 1) v += __shfl_down(v, s, 64);
        if (lane == 0) sred[wv * NCLS + cls] = v;
    }
    __syncthreads();
    if (n < NCLS) {
        float s = 0.0f;
        #pragma unroll
        for (int w = 0; w < 16; ++w) s += sred[w * NCLS + n];
        part[(size_t)(b * 16 + chunk) * NCLS + n] = s;
    }
}

// ---------------------------------------------------------------------------
__global__ __launch_bounds__(256) void k_finish(
    const float* __restrict__ part, const float* __restrict__ bias,
    float* __restrict__ out)
{
    int t = threadIdx.x;
    if (t < BATCH * NCLS) {
        int b = t / NCLS, cls = t % NCLS;
        float s = bias[cls];
        #pragma unroll
        for (int ch = 0; ch < 16; ++ch) s += part[(size_t)(b * 16 + ch) * NCLS + cls];
        out[t] = s;
    }
}

// ---------------------------------------------------------------------------
extern "C" void kernel_launch(void* const* d_in, const int* in_sizes, int n_in,
                              void* d_out, int out_size, void* d_ws, size_t ws_size,
                              hipStream_t stream) {
    const float* data = (const float*)d_in[0];
    const float* fW1  = (const float*)d_in[1];
    const float* fb1  = (const float*)d_in[2];
    const float* fW2  = (const float*)d_in[3];
    const float* fb2  = (const float*)d_in[4];
    const float* fWf  = (const float*)d_in[5];
    const float* fbf  = (const float*)d_in[6];
    float* out = (float*)d_out;

    float* ws   = (float*)d_ws;
    float* Wsp  = ws;                                         // NW*B*NVEC*WPAD = 1,966,080 f
    float* W2T  = Wsp + (size_t)NW * BATCH * NVEC * WPAD;     // NW*NVEC*NHID  =   327,680 f
    float* part = W2T + (size_t)NW * NVEC * NHID;             // 2,560 f

    k_transpose<<<dim3(NVEC / 64, NW), 256, 0, stream>>>(fW2, W2T);
    k_weights<<<dim3(NVEC / 16, NW), 256, 0, stream>>>(
        data, fW1, fb1, W2T, fb2, Wsp);
    k_chain<<<dim3(NDIM / 4, BATCH), 1024, 0, stream>>>(data, Wsp, fWf, part);
    k_finish<<<dim3(1), 256, 0, stream>>>(part, fbf, out);
}